// Round 1
// baseline (411.572 us; speedup 1.0000x reference)
//
#include <hip/hip_runtime.h>
#include <hip/hip_cooperative_groups.h>
#include <math.h>

#define H 2048
#define S 8192
#define NBLK 1024
#define NSLICE 128          // j-slices for u partials
#define JCH (H / NSLICE)    // 16 rows of W per block in phase 1

namespace cg = cooperative_groups;

// Fully fused: u = W^T h  ->  e = enc . u  ->  softmax(e), one cooperative launch.
// grid 1024 x 256 (4 blocks/CU guaranteed by launch_bounds), 3 grid.sync()s.
__global__ __launch_bounds__(256, 4)
void fused_attn(const float* __restrict__ W, const float* __restrict__ h,
                const float* __restrict__ enc, float* __restrict__ out,
                float* __restrict__ u_part, float* __restrict__ u,
                float* __restrict__ red) {
    cg::grid_group grid = cg::this_grid();
    const int b    = blockIdx.x;
    const int tid  = threadIdx.x;
    const int lane = tid & 63;
    const int wave = tid >> 6;

    __shared__ float evals[8];   // this block's 8 row energies (persist across sync)
    __shared__ float wred[4];
    __shared__ float bc[2];

    // ---- phase 1: u_part[js][k] = sum_{j in slice} h[j] * W[j][k]
    // 8 k-chunks x 128 j-slices = 1024 blocks; no atomics, no zero-init needed.
    {
        const int kx = b & 7;
        const int js = b >> 3;
        const int k  = kx * 256 + tid;
        const int j0 = js * JCH;
        float acc = 0.f;
#pragma unroll
        for (int j = j0; j < j0 + JCH; ++j)
            acc += h[j] * W[(size_t)j * H + k];
        u_part[(size_t)js * H + k] = acc;
    }
    grid.sync();

    // ---- phase 1b: u[k] = sum_js u_part[js][k]   (first 8 blocks only)
    {
        const int t = b * 256 + tid;
        if (t < H) {
            float acc = 0.f;
#pragma unroll 8
            for (int js = 0; js < NSLICE; ++js)
                acc += u_part[(size_t)js * H + t];
            u[t] = acc;
        }
    }
    grid.sync();

    // ---- phase 2: e[s] for 8 rows/block (one wave per row, 2 rounds) + block stats
    {
        const float4* u4 = (const float4*)u;
        for (int r = wave; r < 8; r += 4) {
            const int s = b * 8 + r;
            const float4* row = (const float4*)(enc + (size_t)s * H);
            float acc = 0.f;
#pragma unroll
            for (int it = 0; it < 8; ++it) {
                float4 a  = row[lane + it * 64];
                float4 bb = u4 [lane + it * 64];
                acc += a.x * bb.x + a.y * bb.y + a.z * bb.z + a.w * bb.w;
            }
#pragma unroll
            for (int off = 32; off > 0; off >>= 1) acc += __shfl_down(acc, off);
            if (lane == 0) evals[r] = acc;
        }
        __syncthreads();
        if (tid == 0) {
            float m = evals[0];
#pragma unroll
            for (int i = 1; i < 8; ++i) m = fmaxf(m, evals[i]);
            float sb = 0.f;
#pragma unroll
            for (int i = 0; i < 8; ++i) sb += __expf(evals[i] - m);
            red[2 * b]     = m;
            red[2 * b + 1] = sb;
        }
    }
    grid.sync();

    // ---- phase 3: every block redundantly reduces red[1024 pairs] -> (M, Sum),
    // then writes its own 8 outputs from LDS evals.
    {
        float m4[4], s4[4];
        float mt = -INFINITY;
#pragma unroll
        for (int q = 0; q < 4; ++q) {
            const int i = tid + q * 256;
            m4[q] = red[2 * i];
            s4[q] = red[2 * i + 1];
            mt = fmaxf(mt, m4[q]);
        }
#pragma unroll
        for (int off = 32; off > 0; off >>= 1) mt = fmaxf(mt, __shfl_down(mt, off));
        if (lane == 0) wred[wave] = mt;
        __syncthreads();
        if (tid == 0) bc[0] = fmaxf(fmaxf(wred[0], wred[1]), fmaxf(wred[2], wred[3]));
        __syncthreads();
        const float M = bc[0];
        float st = 0.f;
#pragma unroll
        for (int q = 0; q < 4; ++q) st += s4[q] * __expf(m4[q] - M);
#pragma unroll
        for (int off = 32; off > 0; off >>= 1) st += __shfl_down(st, off);
        if (lane == 0) wred[wave] = st;
        __syncthreads();
        if (tid == 0) bc[1] = wred[0] + wred[1] + wred[2] + wred[3];
        __syncthreads();
        const float inv = 1.f / bc[1];
        if (tid < 8) out[b * 8 + tid] = __expf(evals[tid] - M) * inv;
    }
}

// ---------------- fallback path (previous verified 4-dispatch version) ----------------
#define JCHUNK 64

__global__ void wt_h_kernel(const float* __restrict__ W, const float* __restrict__ h,
                            float* __restrict__ u) {
    int k = blockIdx.x * blockDim.x + threadIdx.x;
    int j0 = blockIdx.y * JCHUNK;
    float acc = 0.f;
#pragma unroll 8
    for (int j = j0; j < j0 + JCHUNK; ++j) acc += h[j] * W[(size_t)j * H + k];
    atomicAdd(&u[k], acc);
}

__global__ void enc_dot_kernel(const float* __restrict__ enc, const float* __restrict__ u,
                               float* __restrict__ e) {
    int wave = threadIdx.x >> 6;
    int lane = threadIdx.x & 63;
    int s = blockIdx.x * 4 + wave;
    const float4* row = (const float4*)(enc + (size_t)s * H);
    const float4* u4  = (const float4*)u;
    float acc = 0.f;
#pragma unroll
    for (int i = lane; i < H / 4; i += 64) {
        float4 a = row[i];
        float4 b = u4[i];
        acc += a.x * b.x + a.y * b.y + a.z * b.z + a.w * b.w;
    }
#pragma unroll
    for (int off = 32; off > 0; off >>= 1) acc += __shfl_down(acc, off);
    if (lane == 0) e[s] = acc;
}

__global__ void softmax_kernel(const float* __restrict__ e, float* __restrict__ out) {
    __shared__ float red[16];
    __shared__ float bcast;
    int tid = threadIdx.x;
    int lane = tid & 63;
    int wv = tid >> 6;
    float vals[8];
    float m = -INFINITY;
#pragma unroll
    for (int i = 0; i < 8; ++i) { vals[i] = e[tid + i * 1024]; m = fmaxf(m, vals[i]); }
#pragma unroll
    for (int off = 32; off > 0; off >>= 1) m = fmaxf(m, __shfl_down(m, off));
    if (lane == 0) red[wv] = m;
    __syncthreads();
    if (tid == 0) {
        float mm = red[0];
#pragma unroll
        for (int i = 1; i < 16; ++i) mm = fmaxf(mm, red[i]);
        bcast = mm;
    }
    __syncthreads();
    float M = bcast;
    float ssum = 0.f;
#pragma unroll
    for (int i = 0; i < 8; ++i) { vals[i] = __expf(vals[i] - M); ssum += vals[i]; }
#pragma unroll
    for (int off = 32; off > 0; off >>= 1) ssum += __shfl_down(ssum, off);
    if (lane == 0) red[wv] = ssum;
    __syncthreads();
    if (tid == 0) {
        float t = 0.f;
#pragma unroll
        for (int i = 0; i < 16; ++i) t += red[i];
        bcast = t;
    }
    __syncthreads();
    float inv = 1.f / bcast;
#pragma unroll
    for (int i = 0; i < 8; ++i) out[tid + i * 1024] = vals[i] * inv;
}

extern "C" void kernel_launch(void* const* d_in, const int* in_sizes, int n_in,
                              void* d_out, int out_size, void* d_ws, size_t ws_size,
                              hipStream_t stream) {
    const float* hidden = (const float*)d_in[0];  // (1,1,H)
    const float* enc    = (const float*)d_in[1];  // (S,1,H)
    const float* W      = (const float*)d_in[2];  // (H,H)
    // d_in[3] = b: adds a constant to every energy -> softmax-invariant, ignored.
    float* out = (float*)d_out;                   // (1,1,S)

    float* u_part = (float*)d_ws;                               // 128*2048 floats (1 MB)
    float* u      = u_part + (size_t)NSLICE * H;                // 2048 floats
    float* red    = u + H;                                      // 2048 floats (m,s pairs)

    void* args[] = { (void*)&W, (void*)&hidden, (void*)&enc, (void*)&out,
                     (void*)&u_part, (void*)&u, (void*)&red };
    hipError_t err = hipLaunchCooperativeKernel((void*)fused_attn,
                                                dim3(NBLK), dim3(256),
                                                args, 0, stream);
    if (err != hipSuccess) {
        // fallback: proven 4-dispatch path
        float* e = red;  // reuse: S floats fit well within remaining ws
        hipMemsetAsync(u, 0, H * sizeof(float), stream);
        dim3 g1(H / 256, H / JCHUNK);
        wt_h_kernel<<<g1, 256, 0, stream>>>(W, hidden, u);
        enc_dot_kernel<<<S / 4, 256, 0, stream>>>(enc, u, e);
        softmax_kernel<<<1, 1024, 0, stream>>>(e, out);
    }
}

// Round 2
// 125.252 us; speedup vs baseline: 3.2860x; 3.2860x over previous
//
#include <hip/hip_runtime.h>
#include <math.h>

#define H 2048
#define S 8192
#define KJ 16   // j-rows per wt_h block

// u[k] = sum_j h[j] * W[j*H + k]   (u = W^T h), float4 along k.
// grid: (H/1024 = 2, H/KJ = 128) = 256 blocks x 256 threads.
__global__ __launch_bounds__(256)
void wt_h_kernel(const float* __restrict__ W, const float* __restrict__ h,
                 float* __restrict__ u) {
    const int k4 = blockIdx.x * 256 + threadIdx.x;   // float4 column index
    const int j0 = blockIdx.y * KJ;
    const float4* W4 = (const float4*)W;             // row j: W4[j*(H/4) + k4]
    float4 acc = make_float4(0.f, 0.f, 0.f, 0.f);
#pragma unroll
    for (int j = j0; j < j0 + KJ; ++j) {
        const float hv = h[j];
        const float4 w = W4[(size_t)j * (H / 4) + k4];
        acc.x += hv * w.x; acc.y += hv * w.y;
        acc.z += hv * w.z; acc.w += hv * w.w;
    }
    float* up = u + 4 * (size_t)k4;
    atomicAdd(up + 0, acc.x);
    atomicAdd(up + 1, acc.y);
    atomicAdd(up + 2, acc.z);
    atomicAdd(up + 3, acc.w);
}

// e[s] = enc[s] . u  — one wave per row, 4 rows/block, 2048 blocks.
// Tail: per-block softmax partials (m, sum(exp(e-m))) -> red[2b], red[2b+1].
__global__ __launch_bounds__(256)
void enc_dot_kernel(const float* __restrict__ enc, const float* __restrict__ u,
                    float* __restrict__ e, float* __restrict__ red) {
    __shared__ float ev[4];
    const int wave = threadIdx.x >> 6;
    const int lane = threadIdx.x & 63;
    const int s = blockIdx.x * 4 + wave;
    const float4* row = (const float4*)(enc + (size_t)s * H);
    const float4* u4  = (const float4*)u;
    float acc = 0.f;
#pragma unroll
    for (int it = 0; it < 8; ++it) {
        const float4 a = row[lane + 64 * it];
        const float4 b = u4 [lane + 64 * it];
        acc += a.x * b.x + a.y * b.y + a.z * b.z + a.w * b.w;
    }
#pragma unroll
    for (int off = 32; off > 0; off >>= 1) acc += __shfl_down(acc, off);
    if (lane == 0) { e[s] = acc; ev[wave] = acc; }
    __syncthreads();
    if (threadIdx.x == 0) {
        float m = fmaxf(fmaxf(ev[0], ev[1]), fmaxf(ev[2], ev[3]));
        float sb = 0.f;
#pragma unroll
        for (int i = 0; i < 4; ++i) sb += __expf(ev[i] - m);
        red[2 * blockIdx.x]     = m;
        red[2 * blockIdx.x + 1] = sb;
    }
}

// Each of 32 blocks redundantly reduces the 2048 (m,s) pairs (L2-hot),
// then writes its 256 outputs: out[i] = exp(e[i]-M) / Sum.
__global__ __launch_bounds__(256)
void finalize_kernel(const float* __restrict__ e, const float* __restrict__ red,
                     float* __restrict__ out) {
    __shared__ float wred[4];
    __shared__ float bc[2];
    const int tid = threadIdx.x;
    const int lane = tid & 63;
    const int wave = tid >> 6;
    const float2* pr = (const float2*)red;

    float m8[8], s8[8];
    float mt = -INFINITY;
#pragma unroll
    for (int q = 0; q < 8; ++q) {
        const float2 p = pr[tid + 256 * q];
        m8[q] = p.x; s8[q] = p.y;
        mt = fmaxf(mt, p.x);
    }
#pragma unroll
    for (int off = 32; off > 0; off >>= 1) mt = fmaxf(mt, __shfl_down(mt, off));
    if (lane == 0) wred[wave] = mt;
    __syncthreads();
    if (tid == 0) bc[0] = fmaxf(fmaxf(wred[0], wred[1]), fmaxf(wred[2], wred[3]));
    __syncthreads();
    const float M = bc[0];

    float st = 0.f;
#pragma unroll
    for (int q = 0; q < 8; ++q) st += s8[q] * __expf(m8[q] - M);
#pragma unroll
    for (int off = 32; off > 0; off >>= 1) st += __shfl_down(st, off);
    if (lane == 0) wred[wave] = st;
    __syncthreads();
    if (tid == 0) bc[1] = wred[0] + wred[1] + wred[2] + wred[3];
    __syncthreads();
    const float inv = 1.f / bc[1];

    const int i = blockIdx.x * 256 + tid;
    out[i] = __expf(e[i] - M) * inv;
}

extern "C" void kernel_launch(void* const* d_in, const int* in_sizes, int n_in,
                              void* d_out, int out_size, void* d_ws, size_t ws_size,
                              hipStream_t stream) {
    const float* hidden = (const float*)d_in[0];  // (1,1,H)
    const float* enc    = (const float*)d_in[1];  // (S,1,H)
    const float* W      = (const float*)d_in[2];  // (H,H)
    // d_in[3] = b: adds a constant to every energy -> softmax-invariant, ignored.
    float* out = (float*)d_out;                   // (1,1,S)

    float* u   = (float*)d_ws;                    // H floats
    float* e   = u + H;                           // S floats
    float* red = e + S;                           // 2 * (S/4) floats

    hipMemsetAsync(u, 0, H * sizeof(float), stream);

    wt_h_kernel<<<dim3(H / 1024, H / KJ), 256, 0, stream>>>(W, hidden, u);

    enc_dot_kernel<<<S / 4, 256, 0, stream>>>(enc, u, e, red);

    finalize_kernel<<<S / 256, 256, 0, stream>>>(e, red, out);
}

// Round 3
// 114.967 us; speedup vs baseline: 3.5799x; 1.0895x over previous
//
#include <hip/hip_runtime.h>
#include <math.h>

#define H 2048
#define S 8192
#define NSL 32   // j-slices for u partials
#define KJ (H / NSL)  // 64 j-rows per slice

// u_part[js][k] = sum_{j in slice js} h[j] * W[j*H + k]
// grid (H/256 = 8, NSL = 32), block 256. Coalesced along k, no atomics.
__global__ __launch_bounds__(256)
void wt_h_part(const float* __restrict__ W, const float* __restrict__ h,
               float* __restrict__ u_part) {
    const int k  = blockIdx.x * 256 + threadIdx.x;
    const int j0 = blockIdx.y * KJ;
    float acc = 0.f;
#pragma unroll 8
    for (int j = j0; j < j0 + KJ; ++j)
        acc += h[j] * W[(size_t)j * H + k];
    u_part[(size_t)blockIdx.y * H + k] = acc;
}

// u[k] = sum_js u_part[js][k]  — 8 blocks x 256, 256 KB L2-hot.
__global__ __launch_bounds__(256)
void u_reduce(const float* __restrict__ u_part, float* __restrict__ u) {
    const int k = blockIdx.x * 256 + threadIdx.x;
    float acc = 0.f;
#pragma unroll
    for (int js = 0; js < NSL; ++js)
        acc += u_part[(size_t)js * H + k];
    u[k] = acc;
}

// e[s] = enc[s] . u — one wave per row, 4 rows/block, 2048 blocks.
// Tail: per-block softmax partials (m, sum(exp(e-m))) -> red[2b], red[2b+1].
__global__ __launch_bounds__(256)
void enc_dot_kernel(const float* __restrict__ enc, const float* __restrict__ u,
                    float* __restrict__ e, float* __restrict__ red) {
    __shared__ float ev[4];
    const int wave = threadIdx.x >> 6;
    const int lane = threadIdx.x & 63;
    const int s = blockIdx.x * 4 + wave;
    const float4* row = (const float4*)(enc + (size_t)s * H);
    const float4* u4  = (const float4*)u;
    float acc = 0.f;
#pragma unroll
    for (int it = 0; it < 8; ++it) {
        const float4 a = row[lane + 64 * it];
        const float4 b = u4 [lane + 64 * it];
        acc += a.x * b.x + a.y * b.y + a.z * b.z + a.w * b.w;
    }
#pragma unroll
    for (int off = 32; off > 0; off >>= 1) acc += __shfl_down(acc, off);
    if (lane == 0) { e[s] = acc; ev[wave] = acc; }
    __syncthreads();
    if (threadIdx.x == 0) {
        float m = fmaxf(fmaxf(ev[0], ev[1]), fmaxf(ev[2], ev[3]));
        float sb = 0.f;
#pragma unroll
        for (int i = 0; i < 4; ++i) sb += __expf(ev[i] - m);
        red[2 * blockIdx.x]     = m;
        red[2 * blockIdx.x + 1] = sb;
    }
}

// Each of 32 blocks redundantly reduces the 2048 (m,s) pairs (L2-hot),
// then writes its 256 outputs: out[i] = exp(e[i]-M) / Sum.
__global__ __launch_bounds__(256)
void finalize_kernel(const float* __restrict__ e, const float* __restrict__ red,
                     float* __restrict__ out) {
    __shared__ float wred[4];
    __shared__ float bc[2];
    const int tid = threadIdx.x;
    const int lane = tid & 63;
    const int wave = tid >> 6;
    const float2* pr = (const float2*)red;

    float m8[8], s8[8];
    float mt = -INFINITY;
#pragma unroll
    for (int q = 0; q < 8; ++q) {
        const float2 p = pr[tid + 256 * q];
        m8[q] = p.x; s8[q] = p.y;
        mt = fmaxf(mt, p.x);
    }
#pragma unroll
    for (int off = 32; off > 0; off >>= 1) mt = fmaxf(mt, __shfl_down(mt, off));
    if (lane == 0) wred[wave] = mt;
    __syncthreads();
    if (tid == 0) bc[0] = fmaxf(fmaxf(wred[0], wred[1]), fmaxf(wred[2], wred[3]));
    __syncthreads();
    const float M = bc[0];

    float st = 0.f;
#pragma unroll
    for (int q = 0; q < 8; ++q) st += s8[q] * __expf(m8[q] - M);
#pragma unroll
    for (int off = 32; off > 0; off >>= 1) st += __shfl_down(st, off);
    if (lane == 0) wred[wave] = st;
    __syncthreads();
    if (tid == 0) bc[1] = wred[0] + wred[1] + wred[2] + wred[3];
    __syncthreads();
    const float inv = 1.f / bc[1];

    const int i = blockIdx.x * 256 + tid;
    out[i] = __expf(e[i] - M) * inv;
}

extern "C" void kernel_launch(void* const* d_in, const int* in_sizes, int n_in,
                              void* d_out, int out_size, void* d_ws, size_t ws_size,
                              hipStream_t stream) {
    const float* hidden = (const float*)d_in[0];  // (1,1,H)
    const float* enc    = (const float*)d_in[1];  // (S,1,H)
    const float* W      = (const float*)d_in[2];  // (H,H)
    // d_in[3] = b: adds a constant to every energy -> softmax-invariant, ignored.
    float* out = (float*)d_out;                   // (1,1,S)

    float* u_part = (float*)d_ws;                 // NSL * H floats (256 KB)
    float* u      = u_part + (size_t)NSL * H;     // H floats
    float* e      = u + H;                        // S floats
    float* red    = e + S;                        // 2 * (S/4) floats

    wt_h_part<<<dim3(H / 256, NSL), 256, 0, stream>>>(W, hidden, u_part);

    u_reduce<<<H / 256, 256, 0, stream>>>(u_part, u);

    enc_dot_kernel<<<S / 4, 256, 0, stream>>>(enc, u, e, red);

    finalize_kernel<<<S / 256, 256, 0, stream>>>(e, red, out);
}